// Round 6
// baseline (5092.499 us; speedup 1.0000x reference)
//
#include <hip/hip_runtime.h>
#include <math.h>

namespace {
constexpr int NB  = 512;   // batch
constexpr int NT  = 128;   // timesteps
constexpr int NY  = 16;    // obs dim
constexpr int NZ  = 32;    // latent dim
constexpr int NK  = 8;     // mixture
constexpr int NH  = 64;    // hidden
constexpr int NSUB = 2;    // euler substeps (structural constant in reference)
constexpr int SZ  = 36;    // stride for 32-wide LDS matrices: rows 144B = 16B-aligned
constexpr int SY  = 20;    // stride for Kg (16 cols): rows 80B = 16B-aligned
constexpr float FJIT = 1e-5f;
constexpr float CLOG2PI = 1.8378770664093453f;
}

// Factor the 8x8 lower block at (c0,c0) of src (row stride lds) entirely in
// one thread's registers; write L to dst (row stride ldd) and 1/diag to sinvp.
__device__ __forceinline__ void chol8_1t(const float* src, int lds,
                                         float* dst, int ldd,
                                         int c0, float* sinvp) {
  float a[8][8];
  #pragma unroll
  for (int r = 0; r < 8; ++r)
    #pragma unroll
    for (int c = 0; c <= r; ++c) a[r][c] = src[(c0 + r) * lds + (c0 + c)];
  float iv[8];
  #pragma unroll
  for (int j = 0; j < 8; ++j) {
    const float d  = sqrtf(a[j][j]);
    const float id = 1.0f / d;
    iv[j] = id; a[j][j] = d;
    #pragma unroll
    for (int r = j + 1; r < 8; ++r) a[r][j] *= id;
    #pragma unroll
    for (int k = j + 1; k < 8; ++k)
      #pragma unroll
      for (int r = k; r < 8; ++r) a[r][k] -= a[r][j] * a[k][j];
  }
  #pragma unroll
  for (int r = 0; r < 8; ++r) {
    #pragma unroll
    for (int c = 0; c <= r; ++c) dst[(c0 + r) * ldd + (c0 + c)] = a[r][c];
    sinvp[c0 + r] = iv[r];
  }
}

// Like chol8_1t, but first subtracts the immediately-preceding panel product:
// a[r][c] = mat[c0+r][c0+c] - sum_q dst[c0+r][c0-8+q]*dst[c0+c][c0-8+q].
__device__ __forceinline__ void chol8_trail_1t(const float* mat, int ld,
                                               float* dst, int ldd,
                                               int c0, float* sinvp) {
  float a[8][8];
  #pragma unroll
  for (int r = 0; r < 8; ++r)
    #pragma unroll
    for (int c = 0; c <= r; ++c) {
      float s = mat[(c0 + r) * ld + (c0 + c)];
      #pragma unroll
      for (int q = 0; q < 8; ++q)
        s -= dst[(c0 + r) * ldd + (c0 - 8 + q)] * dst[(c0 + c) * ldd + (c0 - 8 + q)];
      a[r][c] = s;
    }
  float iv[8];
  #pragma unroll
  for (int j = 0; j < 8; ++j) {
    const float d  = sqrtf(a[j][j]);
    const float id = 1.0f / d;
    iv[j] = id; a[j][j] = d;
    #pragma unroll
    for (int r = j + 1; r < 8; ++r) a[r][j] *= id;
    #pragma unroll
    for (int k = j + 1; k < 8; ++k)
      #pragma unroll
      for (int r = k; r < 8; ++r) a[r][k] -= a[r][j] * a[k][j];
  }
  #pragma unroll
  for (int r = 0; r < 8; ++r) {
    #pragma unroll
    for (int c = 0; c <= r; ++c) dst[(c0 + r) * ldd + (c0 + c)] = a[r][c];
    sinvp[c0 + r] = iv[r];
  }
}

// Panel row solve: w = L_diag^{-1} * src[i][c0..c0+7], write to dst[i][c0..c0+7].
__device__ __forceinline__ void panel_row(const float* src, int lds,
                                          float* dst, int ldd,
                                          int c0, int i, const float* sinvp) {
  float w[8];
  #pragma unroll
  for (int q = 0; q < 8; ++q) w[q] = src[i * lds + c0 + q];
  #pragma unroll
  for (int q = 0; q < 8; ++q) {
    float s = w[q];
    #pragma unroll
    for (int p = 0; p < q; ++p) s -= dst[(c0 + q) * ldd + (c0 + p)] * w[p];
    w[q] = s * sinvp[c0 + q];
  }
  #pragma unroll
  for (int q = 0; q < 8; ++q) dst[i * ldd + c0 + q] = w[q];
}

// One block (256 threads) per batch element; ~39 KB LDS -> 4 blocks/CU.
// A_base is read straight from global (L2-resident; zero intra-block reuse).
// All matmul phases use b128/b64 LDS reads with unchanged FMA order ->
// bitwise-identical results to the validated round-5 kernel.
__global__ __launch_bounds__(256, 4)
void kf_scan_kernel(const float* __restrict__ gy,
                    const float* __restrict__ gmask,
                    const float* __restrict__ gtimes,
                    const float* __restrict__ gmu0,
                    const float* __restrict__ gSig0d,
                    const float* __restrict__ gH,
                    const float* __restrict__ gRd,
                    const float* __restrict__ gAb,
                    const float* __restrict__ gW1,
                    const float* __restrict__ gb1,
                    const float* __restrict__ gW2,
                    const float* __restrict__ gb2,
                    const float* __restrict__ gQd,
                    float* __restrict__ out_mus,
                    float* __restrict__ out_Ls,
                    float* __restrict__ out_lp)
{
  const int b   = blockIdx.x;
  const int tid = threadIdx.x;
  const int i8  = tid >> 3;         // 0..31  (row for 32x32 work)
  const int j8  = (tid & 7) << 2;   // 0,4,..,28 (4-col group)

  __shared__ alignas(16) float sW1[NZ][NH];
  __shared__ alignas(16) float sH [NY][SZ];
  __shared__ float sW2[NH][NK];
  __shared__ float sb1v[NH];
  __shared__ float sb2v[NK];
  __shared__ alignas(16) float sRd[NY];
  __shared__ float sQd[NZ];
  __shared__ alignas(16) float Sig[NZ][SZ];     // carried covariance (full)
  __shared__ alignas(16) float Wk [NZ][SZ];     // Sigma_u (lower) / chol32 ws
  __shared__ alignas(16) float T1 [NZ][SZ];     // ImKH / A
  __shared__ alignas(16) float T2 [NZ][SZ];     // ImKH@Sig -> chol32 L (upper zeroed)
  __shared__ alignas(16) float HP [NY][SZ];
  __shared__ float Sm[NY][NY+1];                // S / chol16 workspace
  __shared__ float SL[NY][NY+1];                // chol(S)
  __shared__ alignas(16) float Kg[NZ][SY];      // Kalman gain (z,y)
  __shared__ alignas(16) float muv[NZ];
  __shared__ float muu[NZ], innov[NY], hidv[NH], alphav[NK];
  __shared__ float siv[NZ];
  __shared__ float lpt;

  double lpacc = 0.0;                   // tid0-only log-prob accumulator

  // ---- stage constants into LDS (A_base intentionally NOT staged) ----
  for (int idx = tid; idx < NZ*NH; idx += 256) ((float*)sW1)[idx] = gW1[idx];
  for (int idx = tid; idx < NY*NZ; idx += 256) {
    const int r = idx >> 5, c = idx & 31;
    sH[r][c] = gH[idx];
  }
  for (int idx = tid; idx < NH*NK; idx += 256) ((float*)sW2)[idx] = gW2[idx];
  if (tid < NH) sb1v[tid] = gb1[tid];
  if (tid < NK) sb2v[tid] = gb2[tid];
  if (tid < NY) sRd[tid]  = gRd[tid];
  if (tid < NZ) sQd[tid]  = gQd[tid];
  if (tid < NZ) {
    muv[tid] = gmu0[tid];
    for (int j = 0; j < NZ; ++j) Sig[tid][j] = 0.0f;
    const float r = sqrtf(gSig0d[tid]);   // Sigma = L0 @ L0^T, L0 = diag(sqrt(s0))
    Sig[tid][tid] = r * r;
  }
  const float dtv = gtimes[1] - gtimes[0];
  const float h   = dtv / (float)NSUB;

  float yreg = (tid < NY) ? gy[(size_t)b*NT*NY + tid] : 0.0f;  // y[t=0]
  __syncthreads();

  #pragma unroll 1
  for (int t = 0; t < NT; ++t) {
    const float m = gmask[(size_t)b*NT + t];

    // ---- ph1: innovation + HP = H @ Sig ----
    if (tid < NY) {
      float s = 0.f;
      #pragma unroll
      for (int kb = 0; kb < 8; ++kb) {
        const float4 h4 = *(const float4*)&sH[tid][kb*4];
        const float4 m4 = *(const float4*)&muv[kb*4];
        s += h4.x*m4.x; s += h4.y*m4.y; s += h4.z*m4.z; s += h4.w*m4.w;
      }
      innov[tid] = yreg - s;
    }
    {
      const int i16 = tid >> 4, c0 = (tid & 15) << 1;
      float s0 = 0.f, s1 = 0.f;
      #pragma unroll
      for (int k = 0; k < NZ; ++k) {
        const float hv = sH[i16][k];
        const float2 sg = *(const float2*)&Sig[k][c0];
        s0 += hv * sg.x;
        s1 += hv * sg.y;
      }
      HP[i16][c0] = s0; HP[i16][c0+1] = s1;
    }
    __syncthreads();

    // ---- ph2: S = HP@H^T + R + JIT (wave0 owns top-left 8x8) + fold chol8(0);
    //      prefetch y[t+1] ----
    if (tid < NY && t + 1 < NT) yreg = gy[((size_t)b*NT + t + 1)*NY + tid];
    {
      int r, c;
      if (tid < 64)       { r = tid >> 3;              c = tid & 7; }
      else if (tid < 128) { r = (tid - 64) >> 3;       c = 8 + ((tid - 64) & 7); }
      else                { r = 8 + ((tid - 128) >> 4); c = (tid - 128) & 15; }
      float s = 0.f;
      #pragma unroll
      for (int kb = 0; kb < 8; ++kb) {
        const float4 a4 = *(const float4*)&HP[r][kb*4];
        const float4 b4 = *(const float4*)&sH[c][kb*4];
        s += a4.x*b4.x; s += a4.y*b4.y; s += a4.z*b4.z; s += a4.w*b4.w;
      }
      if (r == c) s += sRd[r] + FJIT;
      Sm[r][c] = s;
    }
    if (tid == 0) chol8_1t(&Sm[0][0], NY+1, &SL[0][0], NY+1, 0, siv);  // wave0 data
    __syncthreads();

    // ---- chol16 rest: panel, then trailing+factor (tid0) ----
    if (tid < 8) panel_row(&Sm[0][0], NY+1, &SL[0][0], NY+1, 0, 8 + tid, siv);
    __syncthreads();
    if (tid == 0) chol8_trail_1t(&Sm[0][0], NY+1, &SL[0][0], NY+1, 8, siv);
    __syncthreads();

    // ---- ph4: solve S X = HP -> Kg = X^T ; mu_u ; logprob (wave 1) ----
    if (tid < NZ) {
      const int c = tid;
      float s[NY], v[NY];
      #pragma unroll
      for (int i = 0; i < NY; ++i) s[i] = HP[i][c];
      #pragma unroll
      for (int i = 0; i < NY; ++i) {          // forward: L v = rhs
        const float vi = s[i] * siv[i];
        v[i] = vi;
        #pragma unroll
        for (int jj = i+1; jj < NY; ++jj) s[jj] -= SL[jj][i] * vi;
      }
      float x[NY];
      #pragma unroll
      for (int i = NY-1; i >= 0; --i) {       // backward: L^T x = v
        const float xi = v[i] * siv[i];
        x[i] = xi;
        #pragma unroll
        for (int jj = 0; jj < i; ++jj) v[jj] -= SL[i][jj] * xi;
      }
      float acc = 0.f;
      #pragma unroll
      for (int i = 0; i < NY; ++i) acc += x[i] * innov[i];
      #pragma unroll
      for (int yb = 0; yb < 4; ++yb)
        *(float4*)&Kg[c][yb*4] = make_float4(x[yb*4], x[yb*4+1], x[yb*4+2], x[yb*4+3]);
      muu[c] = muv[c] + acc;                  // mu_u folded into solve phase
    } else if (tid == 64) {  // wave 1: w = LS^{-1} innov, logprob
      float s[NY];
      #pragma unroll
      for (int i = 0; i < NY; ++i) s[i] = innov[i];
      float sw = 0.f, prod = 1.f;
      #pragma unroll
      for (int i = 0; i < NY; ++i) {
        const float wi = s[i] * siv[i];
        sw += wi * wi;
        prod *= SL[i][i];
        #pragma unroll
        for (int jj = i+1; jj < NY; ++jj) s[jj] -= SL[jj][i] * wi;
      }
      lpt = -0.5f * (sw + NY * CLOG2PI) - logf(prod);
    }
    __syncthreads();

    // ---- ph5': T1 = I - Kg@H ; T2 = Sig - Kg@HP (== ImKH@Sig), fused ----
    {
      float kr[16];
      #pragma unroll
      for (int yb = 0; yb < 4; ++yb) {
        const float4 v = *(const float4*)&Kg[i8][yb*4];
        kr[yb*4] = v.x; kr[yb*4+1] = v.y; kr[yb*4+2] = v.z; kr[yb*4+3] = v.w;
      }
      float4 s1v = make_float4((i8==j8)?1.f:0.f, (i8==j8+1)?1.f:0.f,
                               (i8==j8+2)?1.f:0.f, (i8==j8+3)?1.f:0.f);
      float4 s2v = *(const float4*)&Sig[i8][j8];
      #pragma unroll
      for (int yy = 0; yy < NY; ++yy) {
        const float kv = kr[yy];
        const float4 h4 = *(const float4*)&sH[yy][j8];
        const float4 p4 = *(const float4*)&HP[yy][j8];
        s1v.x -= kv*h4.x; s1v.y -= kv*h4.y; s1v.z -= kv*h4.z; s1v.w -= kv*h4.w;
        s2v.x -= kv*p4.x; s2v.y -= kv*p4.y; s2v.z -= kv*p4.z; s2v.w -= kv*p4.w;
      }
      *(float4*)&T1[i8][j8] = s1v;
      *(float4*)&T2[i8][j8] = s2v;
    }
    __syncthreads();

    // ---- ph7: Wk = T2@T1^T + Kg R Kg^T + JIT (full rows; upper ignored);
    //      fold chol8(blk0) ----
    {
      float t2r[NZ];
      #pragma unroll
      for (int kb = 0; kb < 8; ++kb) {
        const float4 v = *(const float4*)&T2[i8][kb*4];
        t2r[kb*4] = v.x; t2r[kb*4+1] = v.y; t2r[kb*4+2] = v.z; t2r[kb*4+3] = v.w;
      }
      float kr[16];
      #pragma unroll
      for (int yb = 0; yb < 4; ++yb) {
        const float4 v = *(const float4*)&Kg[i8][yb*4];
        kr[yb*4] = v.x; kr[yb*4+1] = v.y; kr[yb*4+2] = v.z; kr[yb*4+3] = v.w;
      }
      float rdr[16];
      #pragma unroll
      for (int yb = 0; yb < 4; ++yb) {
        const float4 v = *(const float4*)&sRd[yb*4];
        rdr[yb*4] = v.x; rdr[yb*4+1] = v.y; rdr[yb*4+2] = v.z; rdr[yb*4+3] = v.w;
      }
      float4 wv;
      float* wvp = &wv.x;
      #pragma unroll
      for (int q = 0; q < 4; ++q) {
        const int j = j8 + q;
        float s = 0.f;
        #pragma unroll
        for (int kb = 0; kb < 8; ++kb) {
          const float4 t1v = *(const float4*)&T1[j][kb*4];
          s += t2r[kb*4]*t1v.x; s += t2r[kb*4+1]*t1v.y;
          s += t2r[kb*4+2]*t1v.z; s += t2r[kb*4+3]*t1v.w;
        }
        float s2 = 0.f;
        #pragma unroll
        for (int yb = 0; yb < 4; ++yb) {
          const float4 kg4 = *(const float4*)&Kg[j][yb*4];
          s2 += kr[yb*4]*rdr[yb*4]*kg4.x;
          s2 += kr[yb*4+1]*rdr[yb*4+1]*kg4.y;
          s2 += kr[yb*4+2]*rdr[yb*4+2]*kg4.z;
          s2 += kr[yb*4+3]*rdr[yb*4+3]*kg4.w;
        }
        s += s2;
        if (i8 == j) s += FJIT;
        wvp[q] = s;
      }
      *(float4*)&Wk[i8][j8] = wv;
    }
    if (tid == 0) chol8_1t(&Wk[0][0], SZ, &T2[0][0], SZ, 0, siv);
    __syncthreads();

    // ---- chol32 rest: 3 x {panel | parallel-trailing + tid0 next diag}.
    //      Last phase also zeroes T2's strict upper (enables full-k L@L^T). ----
    #pragma unroll 1
    for (int blkb = 0; blkb < 3; ++blkb) {
      const int c0 = blkb << 3;
      if (tid < 24 - c0) panel_row(&Wk[0][0], SZ, &T2[0][0], SZ, c0, c0 + 8 + tid, siv);
      __syncthreads();
      if (i8 >= c0 + 16) {
        #pragma unroll
        for (int q4 = 0; q4 < 4; ++q4) {
          const int k = j8 + q4;
          if (k >= c0 + 8 && k <= i8) {
            float s = Wk[i8][k];
            #pragma unroll
            for (int q = 0; q < 8; ++q) s -= T2[i8][c0+q] * T2[k][c0+q];
            Wk[i8][k] = s;
          }
        }
      }
      if (blkb == 2) {   // zero strict upper of T2 (writers disjoint from trail/panel)
        #pragma unroll
        for (int q = 0; q < 4; ++q)
          if (j8 + q > i8) T2[i8][j8+q] = 0.f;
      }
      if (tid == 0) chol8_trail_1t(&Wk[0][0], SZ, &T2[0][0], SZ, c0 + 8, siv);
      __syncthreads();
    }

    // ---- ph9: outputs, Sig = L@L^T (full-k, upper zeros exact), mu blend;
    //      wave0: MLP for substep 0 ----
    if (tid < NZ) {
      const float nm = m * muu[tid] + (1.0f - m) * muv[tid];
      out_mus[((size_t)t*NB + b)*NZ + tid] = nm;
      muv[tid] = nm;
    }
    if (tid == 0) lpacc += (double)(m * lpt);
    {
      const float4 lv = *(const float4*)&T2[i8][j8];   // upper already zeroed
      *(float4*)&out_Ls[(((size_t)t*NB + b)*NZ + i8)*NZ + j8] = lv;
      float t2r[NZ];
      #pragma unroll
      for (int kb = 0; kb < 8; ++kb) {
        const float4 v = *(const float4*)&T2[i8][kb*4];
        t2r[kb*4] = v.x; t2r[kb*4+1] = v.y; t2r[kb*4+2] = v.z; t2r[kb*4+3] = v.w;
      }
      float4 sv;
      float* svp = &sv.x;
      #pragma unroll
      for (int q = 0; q < 4; ++q) {
        const int j = j8 + q;
        float s = 0.f;
        #pragma unroll
        for (int kb = 0; kb < 8; ++kb) {
          const float4 l4 = *(const float4*)&T2[j][kb*4];
          s += t2r[kb*4]*l4.x; s += t2r[kb*4+1]*l4.y;
          s += t2r[kb*4+2]*l4.z; s += t2r[kb*4+3]*l4.w;
        }
        svp[q] = s;
      }
      *(float4*)&Sig[i8][j8] = sv;
    }
    // wave 0: MLP -> alphav (muv wave0-written; per-wave in-order LDS)
    if (tid < NH) {
      __builtin_amdgcn_sched_barrier(0);
      float sacc = sb1v[tid];
      #pragma unroll
      for (int k = 0; k < NZ; ++k) sacc += muv[k] * sW1[k][tid];
      hidv[tid] = tanhf(sacc);
      __builtin_amdgcn_sched_barrier(0);
      const int kk = tid & 7, r0 = (tid >> 3) << 3;
      float part = 0.f;
      #pragma unroll
      for (int j = 0; j < 8; ++j) part += hidv[r0 + j] * sW2[r0 + j][kk];
      part += __shfl_xor(part, 8);
      part += __shfl_xor(part, 16);
      part += __shfl_xor(part, 32);
      float lg[NK];
      #pragma unroll
      for (int q = 0; q < NK; ++q) lg[q] = __shfl(part, (tid & 56) | q) + sb2v[q];
      float mx = lg[0];
      #pragma unroll
      for (int q = 1; q < NK; ++q) mx = fmaxf(mx, lg[q]);
      float se = 0.f;
      #pragma unroll
      for (int q = 0; q < NK; ++q) { lg[q] = expf(lg[q] - mx); se += lg[q]; }
      const float inv = 1.0f / se;
      if (tid == 0) {
        #pragma unroll
        for (int q = 0; q < NK; ++q) alphav[q] = lg[q] * inv;
      }
    }
    __syncthreads();

    // ---- Euler substeps (pred chol skipped: chol(X)@chol(X)^T == X) ----
    #pragma unroll 1
    for (int ss = 0; ss < NSUB; ++ss) {
      // A = sum_k alpha_k A_base[k] -> T1 (A_base straight from global/L2)
      {
        const float* gp = gAb + (size_t)i8*NZ + j8;
        float4 ab[NK];
        #pragma unroll
        for (int k = 0; k < NK; ++k) ab[k] = *(const float4*)(gp + (size_t)k*NZ*NZ);
        float4 a4 = make_float4(0.f, 0.f, 0.f, 0.f);
        #pragma unroll
        for (int k = 0; k < NK; ++k) {
          const float al = alphav[k];
          a4.x += al*ab[k].x; a4.y += al*ab[k].y;
          a4.z += al*ab[k].z; a4.w += al*ab[k].w;
        }
        *(float4*)&T1[i8][j8] = a4;
      }
      __syncthreads();
      // mu2 = mu + h*A@mu ; T2 = A @ Sig
      if (tid < NZ) {
        float s = 0.f;
        #pragma unroll
        for (int kb = 0; kb < 8; ++kb) {
          const float4 t14 = *(const float4*)&T1[tid][kb*4];
          const float4 m4  = *(const float4*)&muv[kb*4];
          s += t14.x*m4.x; s += t14.y*m4.y; s += t14.z*m4.z; s += t14.w*m4.w;
        }
        muu[tid] = muv[tid] + h * s;
      }
      {
        float4 acc = make_float4(0.f, 0.f, 0.f, 0.f);
        #pragma unroll
        for (int k = 0; k < NZ; ++k) {
          const float a = T1[i8][k];
          const float4 sg = *(const float4*)&Sig[k][j8];
          acc.x += a*sg.x; acc.y += a*sg.y; acc.z += a*sg.z; acc.w += a*sg.w;
        }
        *(float4*)&T2[i8][j8] = acc;
      }
      __syncthreads();
      // Sig += h*(T2 + T2^T) + diag(h*Q + JIT) ; mu = mu2 ; wave0: next MLP
      {
        const float4 tv = *(const float4*)&T2[i8][j8];
        float tT[4];
        #pragma unroll
        for (int q = 0; q < 4; ++q) tT[q] = T2[j8+q][i8];
        float4 sg = *(const float4*)&Sig[i8][j8];
        sg.x += h * (tv.x + tT[0]);
        sg.y += h * (tv.y + tT[1]);
        sg.z += h * (tv.z + tT[2]);
        sg.w += h * (tv.w + tT[3]);
        float* sgp = &sg.x;
        #pragma unroll
        for (int q = 0; q < 4; ++q)
          if (i8 == j8 + q) sgp[q] += h * sQd[i8] + FJIT;
        *(float4*)&Sig[i8][j8] = sg;
      }
      if (tid < NZ) muv[tid] = muu[tid];
      if (ss == 0 && tid < NH) {
        __builtin_amdgcn_sched_barrier(0);
        float sacc = sb1v[tid];
        #pragma unroll
        for (int k = 0; k < NZ; ++k) sacc += muv[k] * sW1[k][tid];  // wave0-local
        hidv[tid] = tanhf(sacc);
        __builtin_amdgcn_sched_barrier(0);
        const int kk = tid & 7, r0 = (tid >> 3) << 3;
        float part = 0.f;
        #pragma unroll
        for (int j = 0; j < 8; ++j) part += hidv[r0 + j] * sW2[r0 + j][kk];
        part += __shfl_xor(part, 8);
        part += __shfl_xor(part, 16);
        part += __shfl_xor(part, 32);
        float lg[NK];
        #pragma unroll
        for (int q = 0; q < NK; ++q) lg[q] = __shfl(part, (tid & 56) | q) + sb2v[q];
        float mx = lg[0];
        #pragma unroll
        for (int q = 1; q < NK; ++q) mx = fmaxf(mx, lg[q]);
        float se = 0.f;
        #pragma unroll
        for (int q = 0; q < NK; ++q) { lg[q] = expf(lg[q] - mx); se += lg[q]; }
        const float inv = 1.0f / se;
        if (tid == 0) {
          #pragma unroll
          for (int q = 0; q < NK; ++q) alphav[q] = lg[q] * inv;
        }
      }
      __syncthreads();
    }
  }

  if (tid == 0) out_lp[b] = (float)lpacc;
}

extern "C" void kernel_launch(void* const* d_in, const int* in_sizes, int n_in,
                              void* d_out, int out_size, void* d_ws, size_t ws_size,
                              hipStream_t stream) {
  (void)in_sizes; (void)n_in; (void)d_ws; (void)ws_size; (void)out_size;
  const float* gy     = (const float*)d_in[0];
  const float* gmask  = (const float*)d_in[1];
  const float* gtimes = (const float*)d_in[2];
  const float* gmu0   = (const float*)d_in[3];
  const float* gS0d   = (const float*)d_in[4];
  const float* gH     = (const float*)d_in[5];
  const float* gRd    = (const float*)d_in[6];
  const float* gAb    = (const float*)d_in[7];
  const float* gW1    = (const float*)d_in[8];
  const float* gb1    = (const float*)d_in[9];
  const float* gW2    = (const float*)d_in[10];
  const float* gb2    = (const float*)d_in[11];
  const float* gQd    = (const float*)d_in[12];
  // d_in[13] = n_sub (==2, structural constant)

  float* out = (float*)d_out;
  float* out_mus = out;                                          // (T,B,32)
  float* out_Ls  = out + (size_t)NT*NB*NZ;                       // (T,B,32,32)
  float* out_lp  = out + (size_t)NT*NB*NZ + (size_t)NT*NB*NZ*NZ; // (B,)

  kf_scan_kernel<<<NB, 256, 0, stream>>>(gy, gmask, gtimes, gmu0, gS0d, gH, gRd,
                                         gAb, gW1, gb1, gW2, gb2, gQd,
                                         out_mus, out_Ls, out_lp);
}

// Round 7
// 4785.234 us; speedup vs baseline: 1.0642x; 1.0642x over previous
//
#include <hip/hip_runtime.h>
#include <math.h>

namespace {
constexpr int NB  = 512;   // batch
constexpr int NT  = 128;   // timesteps
constexpr int NY  = 16;    // obs dim
constexpr int NZ  = 32;    // latent dim
constexpr int NK  = 8;     // mixture
constexpr int NH  = 64;    // hidden
constexpr float FJIT = 1e-5f;
constexpr float CLOG2PI = 1.8378770664093453f;
}

// Factor the 8x8 lower block at (c0,c0) of src (row stride lds) entirely in
// one thread's registers; write L to dst (row stride ldd) and 1/diag to sinvp.
__device__ __forceinline__ void chol8_1t(const float* src, int lds,
                                         float* dst, int ldd,
                                         int c0, float* sinvp) {
  float a[8][8];
  #pragma unroll
  for (int r = 0; r < 8; ++r)
    #pragma unroll
    for (int c = 0; c <= r; ++c) a[r][c] = src[(c0 + r) * lds + (c0 + c)];
  float iv[8];
  #pragma unroll
  for (int j = 0; j < 8; ++j) {
    const float d  = sqrtf(a[j][j]);
    const float id = 1.0f / d;
    iv[j] = id; a[j][j] = d;
    #pragma unroll
    for (int r = j + 1; r < 8; ++r) a[r][j] *= id;
    #pragma unroll
    for (int k = j + 1; k < 8; ++k)
      #pragma unroll
      for (int r = k; r < 8; ++r) a[r][k] -= a[r][j] * a[k][j];
  }
  #pragma unroll
  for (int r = 0; r < 8; ++r) {
    #pragma unroll
    for (int c = 0; c <= r; ++c) dst[(c0 + r) * ldd + (c0 + c)] = a[r][c];
    sinvp[c0 + r] = iv[r];
  }
}

// Like chol8_1t, but first subtracts the immediately-preceding panel product.
__device__ __forceinline__ void chol8_trail_1t(const float* mat, int ld,
                                               float* dst, int ldd,
                                               int c0, float* sinvp) {
  float a[8][8];
  #pragma unroll
  for (int r = 0; r < 8; ++r)
    #pragma unroll
    for (int c = 0; c <= r; ++c) {
      float s = mat[(c0 + r) * ld + (c0 + c)];
      #pragma unroll
      for (int q = 0; q < 8; ++q)
        s -= dst[(c0 + r) * ldd + (c0 - 8 + q)] * dst[(c0 + c) * ldd + (c0 - 8 + q)];
      a[r][c] = s;
    }
  float iv[8];
  #pragma unroll
  for (int j = 0; j < 8; ++j) {
    const float d  = sqrtf(a[j][j]);
    const float id = 1.0f / d;
    iv[j] = id; a[j][j] = d;
    #pragma unroll
    for (int r = j + 1; r < 8; ++r) a[r][j] *= id;
    #pragma unroll
    for (int k = j + 1; k < 8; ++k)
      #pragma unroll
      for (int r = k; r < 8; ++r) a[r][k] -= a[r][j] * a[k][j];
  }
  #pragma unroll
  for (int r = 0; r < 8; ++r) {
    #pragma unroll
    for (int c = 0; c <= r; ++c) dst[(c0 + r) * ldd + (c0 + c)] = a[r][c];
    sinvp[c0 + r] = iv[r];
  }
}

// Panel row solve: w = L_diag^{-1} * src[i][c0..c0+7], write to dst[i][c0..c0+7].
__device__ __forceinline__ void panel_row(const float* src, int lds,
                                          float* dst, int ldd,
                                          int c0, int i, const float* sinvp) {
  float w[8];
  #pragma unroll
  for (int q = 0; q < 8; ++q) w[q] = src[i * lds + c0 + q];
  #pragma unroll
  for (int q = 0; q < 8; ++q) {
    float s = w[q];
    #pragma unroll
    for (int p = 0; p < q; ++p) s -= dst[(c0 + q) * ldd + (c0 + p)] * w[p];
    w[q] = s * sinvp[c0 + q];
  }
  #pragma unroll
  for (int q = 0; q < 8; ++q) dst[i * ldd + c0 + q] = w[q];
}

// Wave-3 local: MLP(mu_in) -> softmax alphas (all 64 lanes get all 8, in regs).
// l = lane within wave (0..63). Values bitwise-match the round-5 path.
__device__ __forceinline__ void w3_mlp_alphas(int l, const float* mu_in,
                                              float* hid, const float* W1,
                                              const float* b1, const float* W2,
                                              const float* b2, float* al) {
  float sacc = b1[l];
  #pragma unroll
  for (int k = 0; k < NZ; ++k) sacc += mu_in[k] * W1[k * NH + l];
  hid[l] = tanhf(sacc);
  __builtin_amdgcn_sched_barrier(0);
  const int kk = l & 7, r0 = (l >> 3) << 3;
  float part = 0.f;
  #pragma unroll
  for (int j = 0; j < 8; ++j) part += hid[r0 + j] * W2[(r0 + j) * NK + kk];
  part += __shfl_xor(part, 8);
  part += __shfl_xor(part, 16);
  part += __shfl_xor(part, 32);
  float lg[NK];
  #pragma unroll
  for (int q = 0; q < NK; ++q) lg[q] = __shfl(part, (l & 56) | q) + b2[q];
  float mx = lg[0];
  #pragma unroll
  for (int q = 1; q < NK; ++q) mx = fmaxf(mx, lg[q]);
  float se = 0.f;
  #pragma unroll
  for (int q = 0; q < NK; ++q) { lg[q] = expf(lg[q] - mx); se += lg[q]; }
  const float inv = 1.0f / se;
  #pragma unroll
  for (int q = 0; q < NK; ++q) al[q] = lg[q] * inv;
}

// One block (256 threads) per batch element. Grid-limited to 2 blocks/CU, so
// LDS (<80KB) is free. Wave 3 (tids 192-255) runs the full mu/MLP/A-mix chain
// inside chol32's 6 barrier intervals (it is independent of Sigma_u); trailing
// updates are remapped to tids 8..135. A0 staged in T1 (dead after ph7), A1 in
// TB. Euler becomes 2 pure matmul phases/substep. 18 barriers/step (was 20),
// with both MLP transcendental chains off the critical path. All accumulation
// orders identical to the validated round-5 kernel (bitwise-same output).
__global__ __launch_bounds__(256, 2)
void kf_scan_kernel(const float* __restrict__ gy,
                    const float* __restrict__ gmask,
                    const float* __restrict__ gtimes,
                    const float* __restrict__ gmu0,
                    const float* __restrict__ gSig0d,
                    const float* __restrict__ gH,
                    const float* __restrict__ gRd,
                    const float* __restrict__ gAb,
                    const float* __restrict__ gW1,
                    const float* __restrict__ gb1,
                    const float* __restrict__ gW2,
                    const float* __restrict__ gb2,
                    const float* __restrict__ gQd,
                    float* __restrict__ out_mus,
                    float* __restrict__ out_Ls,
                    float* __restrict__ out_lp)
{
  const int b   = blockIdx.x;
  const int tid = threadIdx.x;
  const int i8  = tid >> 3;         // 0..31  (row for 32x32 work)
  const int j8  = (tid & 7) << 2;   // 0,4,..,28 (4-col group)

  __shared__ float sAb[NK][NZ][NZ+1];   // padded: conflict-free A-mix reads
  __shared__ float sW1[NZ][NH];
  __shared__ float sH [NY][NZ+1];
  __shared__ float sW2[NH][NK];
  __shared__ float sb1v[NH];
  __shared__ float sb2v[NK];
  __shared__ float sRd[NY];
  __shared__ float sQd[NZ];
  __shared__ float Sig[NZ][NZ+1];       // carried covariance
  __shared__ float Wk [NZ][NZ+1];       // Sigma_u (lower) / chol32 ws / euler ping
  __shared__ float T1 [NZ][NZ+1];       // ImKH -> A0
  __shared__ float T2 [NZ][NZ+1];       // ImKH@Sig -> chol32 L -> euler temp
  __shared__ float TB [NZ][NZ+1];       // A1
  __shared__ float HP [NY][NZ+1];
  __shared__ float Sm[NY][NY+1];        // S / chol16 workspace
  __shared__ float SL[NY][NY+1];        // chol(S)
  __shared__ float Kg[NZ][NY+1];        // Kalman gain (z,y)
  __shared__ float muv[NZ], muu[NZ], innov[NY], hidv[NH];
  __shared__ float siv[NZ];
  __shared__ float lpt;

  double lpacc = 0.0;                   // tid0-only log-prob accumulator

  // ---- stage constants into LDS ----
  for (int idx = tid; idx < NK*NZ*NZ; idx += 256) {
    const int k = idx >> 10, r = (idx >> 5) & 31, c = idx & 31;
    sAb[k][r][c] = gAb[idx];
  }
  for (int idx = tid; idx < NZ*NH; idx += 256) ((float*)sW1)[idx] = gW1[idx];
  for (int idx = tid; idx < NY*NZ; idx += 256) {
    const int r = idx >> 5, c = idx & 31;
    sH[r][c] = gH[idx];
  }
  for (int idx = tid; idx < NH*NK; idx += 256) ((float*)sW2)[idx] = gW2[idx];
  if (tid < NH) sb1v[tid] = gb1[tid];
  if (tid < NK) sb2v[tid] = gb2[tid];
  if (tid < NY) sRd[tid]  = gRd[tid];
  if (tid < NZ) sQd[tid]  = gQd[tid];
  if (tid < NZ) {
    muv[tid] = gmu0[tid];
    for (int j = 0; j < NZ; ++j) Sig[tid][j] = 0.0f;
    const float r = sqrtf(gSig0d[tid]);   // Sigma = L0 @ L0^T, L0 = diag(sqrt(s0))
    Sig[tid][tid] = r * r;
  }
  const float dtv = gtimes[1] - gtimes[0];
  const float h   = dtv / 2.0f;           // NSUB == 2

  float yreg = (tid < NY) ? gy[(size_t)b*NT*NY + tid] : 0.0f;  // y[t=0]
  __syncthreads();

  #pragma unroll 1
  for (int t = 0; t < NT; ++t) {
    const float m = gmask[(size_t)b*NT + t];

    // ---- ph1: innovation + HP = H @ Sig ----
    if (tid < NY) {
      float s = 0.f;
      #pragma unroll
      for (int k = 0; k < NZ; ++k) s += sH[tid][k] * muv[k];
      innov[tid] = yreg - s;
    }
    {
      const int i16 = tid >> 4, c0 = (tid & 15) << 1;
      float s0 = 0.f, s1 = 0.f;
      #pragma unroll
      for (int k = 0; k < NZ; ++k) {
        const float hv = sH[i16][k];
        s0 += hv * Sig[k][c0];
        s1 += hv * Sig[k][c0+1];
      }
      HP[i16][c0] = s0; HP[i16][c0+1] = s1;
    }
    __syncthreads();

    // ---- ph2: S = HP@H^T + R + JIT (wave0 owns top-left 8x8) + fold chol8(0);
    //      prefetch y[t+1] ----
    if (tid < NY && t + 1 < NT) yreg = gy[((size_t)b*NT + t + 1)*NY + tid];
    {
      int r, c;
      if (tid < 64)       { r = tid >> 3;              c = tid & 7; }
      else if (tid < 128) { r = (tid - 64) >> 3;       c = 8 + ((tid - 64) & 7); }
      else                { r = 8 + ((tid - 128) >> 4); c = (tid - 128) & 15; }
      float s = 0.f;
      #pragma unroll
      for (int k = 0; k < NZ; ++k) s += HP[r][k] * sH[c][k];
      if (r == c) s += sRd[r] + FJIT;
      Sm[r][c] = s;
    }
    if (tid == 0) chol8_1t(&Sm[0][0], NY+1, &SL[0][0], NY+1, 0, siv);
    __syncthreads();

    // ---- chol16 rest ----
    if (tid < 8) panel_row(&Sm[0][0], NY+1, &SL[0][0], NY+1, 0, 8 + tid, siv);
    __syncthreads();
    if (tid == 0) chol8_trail_1t(&Sm[0][0], NY+1, &SL[0][0], NY+1, 8, siv);
    __syncthreads();

    // ---- ph4: solve S X = HP -> Kg = X^T ; mu_u ; logprob (wave 1) ----
    if (tid < NZ) {
      const int c = tid;
      float s[NY], v[NY];
      #pragma unroll
      for (int i = 0; i < NY; ++i) s[i] = HP[i][c];
      #pragma unroll
      for (int i = 0; i < NY; ++i) {          // forward: L v = rhs
        const float vi = s[i] * siv[i];
        v[i] = vi;
        #pragma unroll
        for (int jj = i+1; jj < NY; ++jj) s[jj] -= SL[jj][i] * vi;
      }
      float x[NY];
      #pragma unroll
      for (int i = NY-1; i >= 0; --i) {       // backward: L^T x = v
        const float xi = v[i] * siv[i];
        x[i] = xi;
        #pragma unroll
        for (int jj = 0; jj < i; ++jj) v[jj] -= SL[i][jj] * xi;
      }
      float acc = 0.f;
      #pragma unroll
      for (int i = 0; i < NY; ++i) { Kg[c][i] = x[i]; acc += x[i] * innov[i]; }
      muu[c] = muv[c] + acc;
    } else if (tid == 64) {  // wave 1: w = LS^{-1} innov, logprob
      float s[NY];
      #pragma unroll
      for (int i = 0; i < NY; ++i) s[i] = innov[i];
      float sw = 0.f, prod = 1.f;
      #pragma unroll
      for (int i = 0; i < NY; ++i) {
        const float wi = s[i] * siv[i];
        sw += wi * wi;
        prod *= SL[i][i];
        #pragma unroll
        for (int jj = i+1; jj < NY; ++jj) s[jj] -= SL[jj][i] * wi;
      }
      lpt = -0.5f * (sw + NY * CLOG2PI) - logf(prod);
    }
    __syncthreads();

    // ---- ph5': T1 = I - Kg@H ; T2 = Sig - Kg@HP (== ImKH@Sig), fused ----
    {
      #pragma unroll
      for (int q = 0; q < 4; ++q) {
        const int j = j8 + q;
        float s1 = (i8 == j) ? 1.0f : 0.0f;
        float s2 = Sig[i8][j];
        #pragma unroll
        for (int yy = 0; yy < NY; ++yy) {
          const float kv = Kg[i8][yy];
          s1 -= kv * sH[yy][j];
          s2 -= kv * HP[yy][j];
        }
        T1[i8][j] = s1;
        T2[i8][j] = s2;
      }
    }
    __syncthreads();

    // ---- ph7: Wk(lower) = T2@T1^T + Kg R Kg^T + JIT ; fold chol8(blk0) ----
    {
      #pragma unroll
      for (int q = 0; q < 4; ++q) {
        const int j = j8 + q;
        if (j <= i8) {
          float s = 0.f;
          #pragma unroll
          for (int k = 0; k < NZ; ++k) s += T2[i8][k] * T1[j][k];
          float s2 = 0.f;
          #pragma unroll
          for (int yy = 0; yy < NY; ++yy) s2 += Kg[i8][yy] * sRd[yy] * Kg[j][yy];
          s += s2;
          if (i8 == j) s += FJIT;
          Wk[i8][j] = s;
        }
      }
    }
    if (tid == 0) chol8_1t(&Wk[0][0], NZ+1, &T2[0][0], NZ+1, 0, siv);
    __syncthreads();

    // ---- chol32 rest (waves 0-2) ∥ mu-chain (wave 3) ----
    // T1 becomes A0, TB becomes A1; muv becomes the blended-then-final mu.
    float al0[NK], al1[NK];
    #pragma unroll
    for (int blkb = 0; blkb < 3; ++blkb) {
      const int c0 = blkb << 3;
      // phase A: panel solve ∥ wave3 {blend+MLP0 | mu1+MLP1 | mu2}
      if (tid < 24 - c0) {
        panel_row(&Wk[0][0], NZ+1, &T2[0][0], NZ+1, c0, c0 + 8 + tid, siv);
      } else if (tid >= 192) {
        const int l = tid - 192;
        if (blkb == 0) {
          if (l < NZ) {
            const float nm = m * muu[l] + (1.0f - m) * muv[l];
            out_mus[((size_t)t*NB + b)*NZ + l] = nm;
            muv[l] = nm;
          }
          __builtin_amdgcn_sched_barrier(0);
          w3_mlp_alphas(l, muv, hidv, &sW1[0][0], sb1v, &sW2[0][0], sb2v, al0);
        } else if (blkb == 1) {
          if (l < NZ) {
            float s = 0.f;
            #pragma unroll
            for (int k = 0; k < NZ; ++k) s += T1[l][k] * muv[k];
            muu[l] = muv[l] + h * s;          // mu1
          }
          __builtin_amdgcn_sched_barrier(0);
          w3_mlp_alphas(l, muu, hidv, &sW1[0][0], sb1v, &sW2[0][0], sb2v, al1);
        } else {
          if (l < NZ) {
            float s = 0.f;
            #pragma unroll
            for (int k = 0; k < NZ; ++k) s += TB[l][k] * muu[k];
            muv[l] = muu[l] + h * s;          // mu2 = final mu for next step
          }
        }
      }
      __syncthreads();
      // phase B: trailing update (tids 8..8+(16-c0)*8) + tid0 next-diag factor
      //          ∥ wave3 {A0->T1 | A1->TB | idle}
      {
        const int nr = (16 - c0) << 3;
        if (tid >= 8 && tid < 8 + nr) {
          const int rr = c0 + 16 + ((tid - 8) >> 3);
          const int jq = ((tid - 8) & 7) << 2;
          #pragma unroll
          for (int q4 = 0; q4 < 4; ++q4) {
            const int k = jq + q4;
            if (k >= c0 + 8 && k <= rr) {
              float s = Wk[rr][k];
              #pragma unroll
              for (int q = 0; q < 8; ++q) s -= T2[rr][c0+q] * T2[k][c0+q];
              Wk[rr][k] = s;
            }
          }
        }
      }
      if (tid == 0) {
        chol8_trail_1t(&Wk[0][0], NZ+1, &T2[0][0], NZ+1, c0 + 8, siv);
      } else if (tid >= 192 && blkb < 2) {
        const int l = tid - 192;
        const float* al = (blkb == 0) ? al0 : al1;
        float* Adst = (blkb == 0) ? &T1[0][0] : &TB[0][0];
        #pragma unroll
        for (int e = 0; e < 16; ++e) {
          const int idx = (l << 4) + e;
          const int r = idx >> 5, c = idx & 31;
          float s = 0.f;
          #pragma unroll
          for (int k = 0; k < NK; ++k) s += al[k] * sAb[k][r][c];
          Adst[r * (NZ+1) + c] = s;
        }
      }
      __syncthreads();
    }

    // ---- ph9: logprob acc, L output, Sig = L@L^T ----
    if (tid == 0) lpacc += (double)(m * lpt);
    {
      float4 lv;
      lv.x = (j8+0 <= i8) ? T2[i8][j8+0] : 0.0f;
      lv.y = (j8+1 <= i8) ? T2[i8][j8+1] : 0.0f;
      lv.z = (j8+2 <= i8) ? T2[i8][j8+2] : 0.0f;
      lv.w = (j8+3 <= i8) ? T2[i8][j8+3] : 0.0f;
      *(float4*)&out_Ls[(((size_t)t*NB + b)*NZ + i8)*NZ + j8] = lv;
      #pragma unroll
      for (int q = 0; q < 4; ++q) {
        const int j = j8 + q;
        const int km = (i8 < j) ? i8 : j;
        float s = 0.f;
        for (int k = 0; k <= km; ++k) s += T2[i8][k] * T2[j][k];
        Sig[i8][j] = s;
      }
    }
    __syncthreads();

    // ---- Euler Sigma phases (A0, A1 pre-staged; mu already advanced) ----
    #pragma unroll
    for (int ss = 0; ss < 2; ++ss) {
      const float (*A)[NZ+1] = (ss == 0) ? T1 : TB;
      // T2 = A @ Sig
      {
        float a0=0.f, a1=0.f, a2=0.f, a3=0.f;
        #pragma unroll
        for (int k = 0; k < NZ; ++k) {
          const float a = A[i8][k];
          a0 += a * Sig[k][j8];
          a1 += a * Sig[k][j8+1];
          a2 += a * Sig[k][j8+2];
          a3 += a * Sig[k][j8+3];
        }
        T2[i8][j8] = a0; T2[i8][j8+1] = a1; T2[i8][j8+2] = a2; T2[i8][j8+3] = a3;
      }
      __syncthreads();
      // Sig += h*(T2 + T2^T) + diag(h*Q + JIT)
      {
        #pragma unroll
        for (int q = 0; q < 4; ++q) {
          const int j = j8 + q;
          float s = Sig[i8][j] + h * (T2[i8][j] + T2[j][i8]);
          if (i8 == j) s += h * sQd[i8] + FJIT;
          Sig[i8][j] = s;
        }
      }
      __syncthreads();
    }
  }

  if (tid == 0) out_lp[b] = (float)lpacc;
}

extern "C" void kernel_launch(void* const* d_in, const int* in_sizes, int n_in,
                              void* d_out, int out_size, void* d_ws, size_t ws_size,
                              hipStream_t stream) {
  (void)in_sizes; (void)n_in; (void)d_ws; (void)ws_size; (void)out_size;
  const float* gy     = (const float*)d_in[0];
  const float* gmask  = (const float*)d_in[1];
  const float* gtimes = (const float*)d_in[2];
  const float* gmu0   = (const float*)d_in[3];
  const float* gS0d   = (const float*)d_in[4];
  const float* gH     = (const float*)d_in[5];
  const float* gRd    = (const float*)d_in[6];
  const float* gAb    = (const float*)d_in[7];
  const float* gW1    = (const float*)d_in[8];
  const float* gb1    = (const float*)d_in[9];
  const float* gW2    = (const float*)d_in[10];
  const float* gb2    = (const float*)d_in[11];
  const float* gQd    = (const float*)d_in[12];
  // d_in[13] = n_sub (==2, structural constant)

  float* out = (float*)d_out;
  float* out_mus = out;                                          // (T,B,32)
  float* out_Ls  = out + (size_t)NT*NB*NZ;                       // (T,B,32,32)
  float* out_lp  = out + (size_t)NT*NB*NZ + (size_t)NT*NB*NZ*NZ; // (B,)

  kf_scan_kernel<<<NB, 256, 0, stream>>>(gy, gmask, gtimes, gmu0, gS0d, gH, gRd,
                                         gAb, gW1, gb1, gW2, gb2, gQd,
                                         out_mus, out_Ls, out_lp);
}